// Round 6
// baseline (1182.755 us; speedup 1.0000x reference)
//
#include <hip/hip_runtime.h>
#include <hip/hip_cooperative_groups.h>

namespace cg = cooperative_groups;

#define NEG_SLOPE 0.2f
#define NBUCK 256
#define PC_EPT 8
#define PC_TILE 2048
#define SMEM_BYTES 33792   // Xs[64][68] (17408) + Ws[64][64] (16384)

// ===========================================================================
// Fused-everything cooperative kernel
// ===========================================================================
struct P {
    const float* x;  const int* ei;
    const float* W1; const float* as1; const float* ad1; const float* b1;
    const float* W2; const float* as2; const float* ad2; const float* b2;
    const float* W3; const float* as3; const float* ad3; const float* b3;
    const float* l1W; const float* l1b; const float* l2W; const float* l2b;
    float* out;
    float* X; float* H; float* AS; float* AD;
    int* row_off; int* csr_src; int* bhist; int* gcurs; int* pairs;
    int N, E, B, ntiles;
};

// ---- GEMM phase: out[N,64] = x@W, plus alpha_s/alpha_d ----------------
__device__ __forceinline__ void gemm_phase(
    const float* __restrict__ x, const float* __restrict__ W,
    const float* __restrict__ a_src, const float* __restrict__ a_dst,
    float* __restrict__ out, float* __restrict__ alpha_s,
    float* __restrict__ alpha_d, int N, int ntiles,
    int tile0, int tstride, char* smembuf)
{
    float (*Xs)[68] = (float (*)[68])smembuf;
    float* Ws = (float*)(smembuf + 17408);
    const int t  = threadIdx.x;
    const int tx = t & 15, ty = t >> 4;

    for (int i = t; i < 1024; i += 256)
        ((float4*)Ws)[i] = ((const float4*)W)[i];
    const float4 asv = *(const float4*)&a_src[tx * 4];
    const float4 adv = *(const float4*)&a_dst[tx * 4];

    for (int tile = tile0; tile < ntiles; tile += tstride) {
        const int row0 = tile * 64;
        for (int i = t; i < 1024; i += 256) {
            int r = i >> 4, c4 = (i & 15) * 4;
            float4 v = {0.f, 0.f, 0.f, 0.f};
            if (row0 + r < N) v = *(const float4*)&x[(size_t)(row0 + r) * 64 + c4];
            *(float4*)&Xs[r][c4] = v;
        }
        __syncthreads();

        float acc[4][4] = {{0,0,0,0},{0,0,0,0},{0,0,0,0},{0,0,0,0}};
#pragma unroll 8
        for (int k = 0; k < 64; ++k) {
            const float4 wv = *(const float4*)&Ws[k * 64 + tx * 4];
            const float x0 = Xs[ty * 4 + 0][k];
            const float x1 = Xs[ty * 4 + 1][k];
            const float x2 = Xs[ty * 4 + 2][k];
            const float x3 = Xs[ty * 4 + 3][k];
            acc[0][0] += x0 * wv.x; acc[0][1] += x0 * wv.y;
            acc[0][2] += x0 * wv.z; acc[0][3] += x0 * wv.w;
            acc[1][0] += x1 * wv.x; acc[1][1] += x1 * wv.y;
            acc[1][2] += x1 * wv.z; acc[1][3] += x1 * wv.w;
            acc[2][0] += x2 * wv.x; acc[2][1] += x2 * wv.y;
            acc[2][2] += x2 * wv.z; acc[2][3] += x2 * wv.w;
            acc[3][0] += x3 * wv.x; acc[3][1] += x3 * wv.y;
            acc[3][2] += x3 * wv.z; acc[3][3] += x3 * wv.w;
        }

#pragma unroll
        for (int i = 0; i < 4; ++i) {
            const int r = row0 + ty * 4 + i;
            if (r < N) {
                float4 o = {acc[i][0], acc[i][1], acc[i][2], acc[i][3]};
                *(float4*)&out[(size_t)r * 64 + tx * 4] = o;
            }
        }
#pragma unroll
        for (int i = 0; i < 4; ++i) {
            float s = acc[i][0]*asv.x + acc[i][1]*asv.y
                    + acc[i][2]*asv.z + acc[i][3]*asv.w;
            float d = acc[i][0]*adv.x + acc[i][1]*adv.y
                    + acc[i][2]*adv.z + acc[i][3]*adv.w;
#pragma unroll
            for (int off = 1; off < 16; off <<= 1) {
                s += __shfl_xor(s, off, 16);
                d += __shfl_xor(d, off, 16);
            }
            const int r = row0 + ty * 4 + i;
            if (tx == 0 && r < N) { alpha_s[r] = s; alpha_d[r] = d; }
        }
        __syncthreads();   // before next tile overwrites Xs
    }
}

// ---- aggregation phase: X[d] = relu(softmax-agg(H[src]) + bias) -------
__device__ __forceinline__ void agg_phase(
    const int* __restrict__ row_off, const int* __restrict__ csr_src,
    const float* __restrict__ h, const float* __restrict__ as,
    const float* __restrict__ ad, const float* __restrict__ bias,
    float* __restrict__ out, int N)
{
    const int lane = threadIdx.x & 63;
    const int g    = lane >> 4;
    const int gl   = lane & 15;
    const int gw0  = (blockIdx.x * 256 + threadIdx.x) >> 6;
    const int tot  = (gridDim.x * 256) >> 6;

    for (int d = gw0; d < N; d += tot) {
        const int beg = row_off[d], end = row_off[d + 1];
        const float add = ad[d];

        float  den = 0.f;
        float4 acc = {0.f, 0.f, 0.f, 0.f};
        int srcp = (beg + g < end) ? csr_src[beg + g] : 0;

        for (int e0 = beg; e0 < end; e0 += 4) {
            const bool valid = (e0 + g < end);
            const int  s     = srcp;
            const int  en    = e0 + 4 + g;
            srcp = (en < end) ? csr_src[en] : 0;

            const float  av = as[s];
            const float4 hv = *(const float4*)&h[(size_t)s * 64 + gl * 4];

            float ev = av + add;
            ev = (ev >= 0.f) ? ev : NEG_SLOPE * ev;
            const float w = valid ? __expf(ev) : 0.f;

            den += w;
            acc.x += w * hv.x; acc.y += w * hv.y;
            acc.z += w * hv.z; acc.w += w * hv.w;
        }

#pragma unroll
        for (int off = 16; off <= 32; off <<= 1) {
            acc.x += __shfl_xor(acc.x, off, 64);
            acc.y += __shfl_xor(acc.y, off, 64);
            acc.z += __shfl_xor(acc.z, off, 64);
            acc.w += __shfl_xor(acc.w, off, 64);
            den   += __shfl_xor(den,   off, 64);
        }

        if (g == 0) {
            const float4 bvv = *(const float4*)&bias[gl * 4];
            const float inv = (den > 0.f) ? (1.f / den) : 0.f;
            float4 o;
            o.x = fmaxf(acc.x * inv + bvv.x, 0.f);
            o.y = fmaxf(acc.y * inv + bvv.y, 0.f);
            o.z = fmaxf(acc.z * inv + bvv.z, 0.f);
            o.w = fmaxf(acc.w * inv + bvv.w, 0.f);
            *(float4*)&out[(size_t)d * 64 + gl * 4] = o;
        }
    }
}

// ---- partition phase (coarse bucket binning) --------------------------
__device__ __forceinline__ void partition_phase(const P& p, char* smembuf)
{
    int* sc   = (int*)smembuf;
    int* hist = sc + 256;
    int* base = hist + 256;
    const int t = threadIdx.x;

    const int bh = p.bhist[t];
    sc[t] = bh; __syncthreads();
    for (int off = 1; off < 256; off <<= 1) {
        int v = sc[t];
        if (t >= off) v += sc[t - off];
        __syncthreads(); sc[t] = v; __syncthreads();
    }
    const int bbase = sc[t] - bh;

    const int npt = (p.E + PC_TILE - 1) / PC_TILE;
    for (int tile = blockIdx.x; tile < npt; tile += gridDim.x) {
        hist[t] = 0;
        __syncthreads();
        const int tile0 = tile * PC_TILE;
        int sv[PC_EPT], dv[PC_EPT], rk[PC_EPT];
#pragma unroll
        for (int i = 0; i < PC_EPT; ++i) {
            const int e = tile0 + i * 256 + t;
            if (e < p.E) {
                sv[i] = p.ei[e];
                dv[i] = p.ei[p.E + e];
                rk[i] = atomicAdd(&hist[dv[i] >> 8], 1);
            } else dv[i] = -1;
        }
        __syncthreads();
        if (hist[t] > 0) base[t] = bbase + atomicAdd(&p.gcurs[t], hist[t]);
        __syncthreads();
#pragma unroll
        for (int i = 0; i < PC_EPT; ++i) {
            if (dv[i] >= 0) {
                const int b = dv[i] >> 8;
                p.pairs[base[b] + rk[i]] = sv[i] | ((dv[i] & 255) << 16);
            }
        }
        __syncthreads();
    }
}

// ---- scatter phase (in-bucket CSR finalization) -----------------------
__device__ __forceinline__ void scatter_phase(const P& p, char* smembuf)
{
    int* sc  = (int*)smembuf;
    int* cnt = sc + 256;
    int* cur = cnt + 256;
    const int t = threadIdx.x;

    const int bh = p.bhist[t];
    sc[t] = bh; __syncthreads();
    for (int off = 1; off < 256; off <<= 1) {
        int v = sc[t];
        if (t >= off) v += sc[t - off];
        __syncthreads(); sc[t] = v; __syncthreads();
    }
    sc[t] -= bh;
    __syncthreads();

    for (int b = blockIdx.x; b < p.B; b += gridDim.x) {
        cnt[t] = 0;
        __syncthreads();
        const int sb = sc[b];
        const int se = sb + p.bhist[b];
        for (int pp = sb + t; pp < se; pp += 256)
            atomicAdd(&cnt[p.pairs[pp] >> 16], 1);
        __syncthreads();

        const int c = cnt[t];
        cur[t] = c; __syncthreads();
        for (int off = 1; off < 256; off <<= 1) {
            int v = cur[t];
            if (t >= off) v += cur[t - off];
            __syncthreads(); cur[t] = v; __syncthreads();
        }
        const int node_off = sb + cur[t] - c;
        __syncthreads();
        cur[t] = node_off;
        const int n = b * 256 + t;
        if (n < p.N) p.row_off[n] = node_off;
        __syncthreads();

        for (int pp = sb + t; pp < se; pp += 256) {
            const int v = p.pairs[pp];
            const int pos = atomicAdd(&cur[v >> 16], 1);
            p.csr_src[pos] = v & 0xFFFF;
        }
        __syncthreads();
    }
    if (blockIdx.x == 0 && t == 0) p.row_off[p.N] = p.E;
}

// ---- head phase: out = relu(X@W1+b1)@W2+b2 ----------------------------
__device__ __forceinline__ void head_phase(const P& p, char* smembuf)
{
    float (*Xs)[68] = (float (*)[68])smembuf;
    float* W1s = (float*)(smembuf + 17408);
    const int t  = threadIdx.x;
    const int tx = t & 15, ty = t >> 4;

    for (int i = t; i < 1024; i += 256)
        ((float4*)W1s)[i] = ((const float4*)p.l1W)[i];
    const float4 b1v = *(const float4*)&p.l1b[tx * 4];
    const float2 b2v = *(const float2*)&p.l2b[tx * 2];

    for (int tile = blockIdx.x; tile < p.ntiles; tile += gridDim.x) {
        const int row0 = tile * 64;
        for (int i = t; i < 1024; i += 256) {
            int r = i >> 4, c4 = (i & 15) * 4;
            float4 v = {0.f, 0.f, 0.f, 0.f};
            if (row0 + r < p.N) v = *(const float4*)&p.X[(size_t)(row0 + r) * 64 + c4];
            *(float4*)&Xs[r][c4] = v;
        }
        __syncthreads();

        float acc[4][4] = {{0,0,0,0},{0,0,0,0},{0,0,0,0},{0,0,0,0}};
#pragma unroll 8
        for (int k = 0; k < 64; ++k) {
            const float4 wv = *(const float4*)&W1s[k * 64 + tx * 4];
            const float x0 = Xs[ty * 4 + 0][k];
            const float x1 = Xs[ty * 4 + 1][k];
            const float x2 = Xs[ty * 4 + 2][k];
            const float x3 = Xs[ty * 4 + 3][k];
            acc[0][0] += x0 * wv.x; acc[0][1] += x0 * wv.y;
            acc[0][2] += x0 * wv.z; acc[0][3] += x0 * wv.w;
            acc[1][0] += x1 * wv.x; acc[1][1] += x1 * wv.y;
            acc[1][2] += x1 * wv.z; acc[1][3] += x1 * wv.w;
            acc[2][0] += x2 * wv.x; acc[2][1] += x2 * wv.y;
            acc[2][2] += x2 * wv.z; acc[2][3] += x2 * wv.w;
            acc[3][0] += x3 * wv.x; acc[3][1] += x3 * wv.y;
            acc[3][2] += x3 * wv.z; acc[3][3] += x3 * wv.w;
        }
        __syncthreads();   // done reading Xs as X
#pragma unroll
        for (int i = 0; i < 4; ++i) {
            Xs[ty * 4 + i][tx * 4 + 0] = fmaxf(acc[i][0] + b1v.x, 0.f);
            Xs[ty * 4 + i][tx * 4 + 1] = fmaxf(acc[i][1] + b1v.y, 0.f);
            Xs[ty * 4 + i][tx * 4 + 2] = fmaxf(acc[i][2] + b1v.z, 0.f);
            Xs[ty * 4 + i][tx * 4 + 3] = fmaxf(acc[i][3] + b1v.w, 0.f);
        }
        __syncthreads();

        float a2[4][2] = {{0,0},{0,0},{0,0},{0,0}};
#pragma unroll 8
        for (int k = 0; k < 64; ++k) {
            const float2 wv = *(const float2*)&p.l2W[k * 32 + tx * 2];   // L2-hot
            const float t0 = Xs[ty * 4 + 0][k];
            const float t1 = Xs[ty * 4 + 1][k];
            const float t2 = Xs[ty * 4 + 2][k];
            const float t3 = Xs[ty * 4 + 3][k];
            a2[0][0] += t0 * wv.x; a2[0][1] += t0 * wv.y;
            a2[1][0] += t1 * wv.x; a2[1][1] += t1 * wv.y;
            a2[2][0] += t2 * wv.x; a2[2][1] += t2 * wv.y;
            a2[3][0] += t3 * wv.x; a2[3][1] += t3 * wv.y;
        }
#pragma unroll
        for (int i = 0; i < 4; ++i) {
            const int r = row0 + ty * 4 + i;
            if (r < p.N) {
                float2 o = {a2[i][0] + b2v.x, a2[i][1] + b2v.y};
                *(float2*)&p.out[(size_t)r * 32 + tx * 2] = o;
            }
        }
        __syncthreads();   // before next tile overwrites Xs
    }
}

__global__ __launch_bounds__(256, 4) void fused_all(P p)
{
    cg::grid_group grid = cg::this_grid();
    __shared__ __align__(16) char smembuf[SMEM_BYTES];
    const int t = threadIdx.x;

    // P0: bucket histogram (blocks < HB)  ||  gemm layer 1 (blocks >= HB)
    const int HB = 128;
    if ((int)blockIdx.x < HB) {
        int* hsh = (int*)smembuf;
        hsh[t] = 0; __syncthreads();
        for (int e = blockIdx.x * 256 + t; e < p.E; e += HB * 256)
            atomicAdd(&hsh[((unsigned)p.ei[p.E + e]) >> 8], 1);
        __syncthreads();
        if (hsh[t]) atomicAdd(&p.bhist[t], hsh[t]);
    } else {
        gemm_phase(p.x, p.W1, p.as1, p.ad1, p.H, p.AS, p.AD, p.N, p.ntiles,
                   blockIdx.x - HB, gridDim.x - HB, smembuf);
    }
    grid.sync();

    partition_phase(p, smembuf);
    grid.sync();

    scatter_phase(p, smembuf);
    grid.sync();

    agg_phase(p.row_off, p.csr_src, p.H, p.AS, p.AD, p.b1, p.X, p.N);
    grid.sync();

    gemm_phase(p.X, p.W2, p.as2, p.ad2, p.H, p.AS, p.AD, p.N, p.ntiles,
               blockIdx.x, gridDim.x, smembuf);
    grid.sync();

    agg_phase(p.row_off, p.csr_src, p.H, p.AS, p.AD, p.b2, p.X, p.N);
    grid.sync();

    gemm_phase(p.X, p.W3, p.as3, p.ad3, p.H, p.AS, p.AD, p.N, p.ntiles,
               blockIdx.x, gridDim.x, smembuf);
    grid.sync();

    agg_phase(p.row_off, p.csr_src, p.H, p.AS, p.AD, p.b3, p.X, p.N);
    grid.sync();

    head_phase(p, smembuf);
}

// ===========================================================================
// Fallback path (proven R5 kernels) — used only if cooperative launch fails
// ===========================================================================
template <bool RELU, bool WANT_ALPHA>
__global__ __launch_bounds__(256) void gemm64(
    const float* __restrict__ x, const float* __restrict__ W,
    const float* __restrict__ bias,
    const float* __restrict__ a_src, const float* __restrict__ a_dst,
    float* __restrict__ out, float* __restrict__ alpha_s,
    float* __restrict__ alpha_d, int N)
{
    __shared__ float Xs[64][68];
    __shared__ float Ws[64][64];

    const int row0 = blockIdx.x * 64;
    for (int i = threadIdx.x; i < 1024; i += 256)
        ((float4*)Ws)[i] = ((const float4*)W)[i];
    for (int i = threadIdx.x; i < 1024; i += 256) {
        int r = i >> 4, c4 = (i & 15) * 4;
        float4 v = {0.f, 0.f, 0.f, 0.f};
        if (row0 + r < N) v = *(const float4*)&x[(size_t)(row0 + r) * 64 + c4];
        *(float4*)&Xs[r][c4] = v;
    }
    __syncthreads();

    const int tx = threadIdx.x & 15;
    const int ty = threadIdx.x >> 4;
    float acc[4][4] = {{0,0,0,0},{0,0,0,0},{0,0,0,0},{0,0,0,0}};
#pragma unroll 8
    for (int k = 0; k < 64; ++k) {
        const float4 wv = *(const float4*)&Ws[k][tx * 4];
        const float x0 = Xs[ty * 4 + 0][k];
        const float x1 = Xs[ty * 4 + 1][k];
        const float x2 = Xs[ty * 4 + 2][k];
        const float x3 = Xs[ty * 4 + 3][k];
        acc[0][0] += x0 * wv.x; acc[0][1] += x0 * wv.y;
        acc[0][2] += x0 * wv.z; acc[0][3] += x0 * wv.w;
        acc[1][0] += x1 * wv.x; acc[1][1] += x1 * wv.y;
        acc[1][2] += x1 * wv.z; acc[1][3] += x1 * wv.w;
        acc[2][0] += x2 * wv.x; acc[2][1] += x2 * wv.y;
        acc[2][2] += x2 * wv.z; acc[2][3] += x2 * wv.w;
        acc[3][0] += x3 * wv.x; acc[3][1] += x3 * wv.y;
        acc[3][2] += x3 * wv.z; acc[3][3] += x3 * wv.w;
    }

    float4 bv = {0.f, 0.f, 0.f, 0.f};
    if (bias) bv = *(const float4*)&bias[tx * 4];
#pragma unroll
    for (int i = 0; i < 4; ++i) {
        const int r = row0 + ty * 4 + i;
        if (r < N) {
            float4 o = {acc[i][0] + bv.x, acc[i][1] + bv.y,
                        acc[i][2] + bv.z, acc[i][3] + bv.w};
            if (RELU) {
                o.x = fmaxf(o.x, 0.f); o.y = fmaxf(o.y, 0.f);
                o.z = fmaxf(o.z, 0.f); o.w = fmaxf(o.w, 0.f);
            }
            *(float4*)&out[(size_t)r * 64 + tx * 4] = o;
        }
    }
    if (WANT_ALPHA) {
        const float4 asv = *(const float4*)&a_src[tx * 4];
        const float4 adv = *(const float4*)&a_dst[tx * 4];
#pragma unroll
        for (int i = 0; i < 4; ++i) {
            float s = acc[i][0]*asv.x + acc[i][1]*asv.y
                    + acc[i][2]*asv.z + acc[i][3]*asv.w;
            float d = acc[i][0]*adv.x + acc[i][1]*adv.y
                    + acc[i][2]*adv.z + acc[i][3]*adv.w;
#pragma unroll
            for (int off = 1; off < 16; off <<= 1) {
                s += __shfl_xor(s, off, 16);
                d += __shfl_xor(d, off, 16);
            }
            const int r = row0 + ty * 4 + i;
            if (tx == 0 && r < N) { alpha_s[r] = s; alpha_d[r] = d; }
        }
    }
}

__global__ __launch_bounds__(256) void gemm_head(
    const float* __restrict__ X, const float* __restrict__ W1,
    const float* __restrict__ b1, const float* __restrict__ W2,
    const float* __restrict__ b2, float* __restrict__ out, int N)
{
    __shared__ float Xs[64][68];
    __shared__ float W1s[64][64];
    __shared__ float W2s[64][32];
    const int row0 = blockIdx.x * 64;

    for (int i = threadIdx.x; i < 1024; i += 256)
        ((float4*)W1s)[i] = ((const float4*)W1)[i];
    for (int i = threadIdx.x; i < 512; i += 256)
        ((float4*)W2s)[i] = ((const float4*)W2)[i];
    for (int i = threadIdx.x; i < 1024; i += 256) {
        int r = i >> 4, c4 = (i & 15) * 4;
        float4 v = {0.f, 0.f, 0.f, 0.f};
        if (row0 + r < N) v = *(const float4*)&X[(size_t)(row0 + r) * 64 + c4];
        *(float4*)&Xs[r][c4] = v;
    }
    __syncthreads();

    const int tx = threadIdx.x & 15;
    const int ty = threadIdx.x >> 4;
    float acc[4][4] = {{0,0,0,0},{0,0,0,0},{0,0,0,0},{0,0,0,0}};
#pragma unroll 8
    for (int k = 0; k < 64; ++k) {
        const float4 wv = *(const float4*)&W1s[k][tx * 4];
        const float x0 = Xs[ty * 4 + 0][k];
        const float x1 = Xs[ty * 4 + 1][k];
        const float x2 = Xs[ty * 4 + 2][k];
        const float x3 = Xs[ty * 4 + 3][k];
        acc[0][0] += x0 * wv.x; acc[0][1] += x0 * wv.y;
        acc[0][2] += x0 * wv.z; acc[0][3] += x0 * wv.w;
        acc[1][0] += x1 * wv.x; acc[1][1] += x1 * wv.y;
        acc[1][2] += x1 * wv.z; acc[1][3] += x1 * wv.w;
        acc[2][0] += x2 * wv.x; acc[2][1] += x2 * wv.y;
        acc[2][2] += x2 * wv.z; acc[2][3] += x2 * wv.w;
        acc[3][0] += x3 * wv.x; acc[3][1] += x3 * wv.y;
        acc[3][2] += x3 * wv.z; acc[3][3] += x3 * wv.w;
    }
    const float4 bv = *(const float4*)&b1[tx * 4];
    __syncthreads();
#pragma unroll
    for (int i = 0; i < 4; ++i) {
        Xs[ty * 4 + i][tx * 4 + 0] = fmaxf(acc[i][0] + bv.x, 0.f);
        Xs[ty * 4 + i][tx * 4 + 1] = fmaxf(acc[i][1] + bv.y, 0.f);
        Xs[ty * 4 + i][tx * 4 + 2] = fmaxf(acc[i][2] + bv.z, 0.f);
        Xs[ty * 4 + i][tx * 4 + 3] = fmaxf(acc[i][3] + bv.w, 0.f);
    }
    __syncthreads();

    float a2[4][2] = {{0,0},{0,0},{0,0},{0,0}};
#pragma unroll 8
    for (int k = 0; k < 64; ++k) {
        const float2 wv = *(const float2*)&W2s[k][tx * 2];
        const float t0 = Xs[ty * 4 + 0][k];
        const float t1 = Xs[ty * 4 + 1][k];
        const float t2 = Xs[ty * 4 + 2][k];
        const float t3 = Xs[ty * 4 + 3][k];
        a2[0][0] += t0 * wv.x; a2[0][1] += t0 * wv.y;
        a2[1][0] += t1 * wv.x; a2[1][1] += t1 * wv.y;
        a2[2][0] += t2 * wv.x; a2[2][1] += t2 * wv.y;
        a2[3][0] += t3 * wv.x; a2[3][1] += t3 * wv.y;
    }
    const float2 b2v = *(const float2*)&b2[tx * 2];
#pragma unroll
    for (int i = 0; i < 4; ++i) {
        const int r = row0 + ty * 4 + i;
        if (r < N) {
            float2 o = {a2[i][0] + b2v.x, a2[i][1] + b2v.y};
            *(float2*)&out[(size_t)r * 32 + tx * 2] = o;
        }
    }
}

__global__ __launch_bounds__(256) void bucket_hist(
    const int* __restrict__ ei, int E, int* __restrict__ bhist)
{
    __shared__ int h[NBUCK];
    const int t = threadIdx.x;
    h[t] = 0;
    __syncthreads();
    for (int e = blockIdx.x * 256 + t; e < E; e += gridDim.x * 256)
        atomicAdd(&h[((unsigned)ei[E + e]) >> 8], 1);
    __syncthreads();
    if (h[t]) atomicAdd(&bhist[t], h[t]);
}

__global__ __launch_bounds__(256) void partition_coarse(
    const int* __restrict__ ei, int E, const int* __restrict__ bhist,
    int* __restrict__ gcurs, int* __restrict__ pairs)
{
    __shared__ int sc[NBUCK];
    __shared__ int hist[NBUCK];
    __shared__ int base[NBUCK];
    const int t = threadIdx.x;

    const int bh = bhist[t];
    sc[t] = bh; __syncthreads();
    for (int off = 1; off < 256; off <<= 1) {
        int v = sc[t];
        if (t >= off) v += sc[t - off];
        __syncthreads(); sc[t] = v; __syncthreads();
    }
    const int bbase = sc[t] - bh;
    hist[t] = 0;
    __syncthreads();

    const int tile0 = blockIdx.x * PC_TILE;
    int sv[PC_EPT], dv[PC_EPT], rk[PC_EPT];
#pragma unroll
    for (int i = 0; i < PC_EPT; ++i) {
        const int e = tile0 + i * 256 + t;
        if (e < E) {
            sv[i] = ei[e];
            dv[i] = ei[E + e];
            rk[i] = atomicAdd(&hist[dv[i] >> 8], 1);
        } else dv[i] = -1;
    }
    __syncthreads();
    if (hist[t] > 0) base[t] = bbase + atomicAdd(&gcurs[t], hist[t]);
    __syncthreads();
#pragma unroll
    for (int i = 0; i < PC_EPT; ++i) {
        if (dv[i] >= 0) {
            const int b = dv[i] >> 8;
            pairs[base[b] + rk[i]] = sv[i] | ((dv[i] & 255) << 16);
        }
    }
}

__global__ __launch_bounds__(256) void fine_scatter(
    const int* __restrict__ bhist, const int* __restrict__ pairs,
    int N, int E, int* __restrict__ row_off, int* __restrict__ csr_src)
{
    __shared__ int sc[NBUCK];
    __shared__ int cnt[NBUCK];
    __shared__ int cur[NBUCK];
    const int t = threadIdx.x, b = blockIdx.x;

    const int bh = bhist[t];
    sc[t] = bh; __syncthreads();
    for (int off = 1; off < 256; off <<= 1) {
        int v = sc[t];
        if (t >= off) v += sc[t - off];
        __syncthreads(); sc[t] = v; __syncthreads();
    }
    sc[t] -= bh;
    cnt[t] = 0;
    __syncthreads();

    const int sb = sc[b];
    const int se = sb + bhist[b];
    for (int p = sb + t; p < se; p += 256)
        atomicAdd(&cnt[pairs[p] >> 16], 1);
    __syncthreads();

    const int c = cnt[t];
    cur[t] = c; __syncthreads();
    for (int off = 1; off < 256; off <<= 1) {
        int v = cur[t];
        if (t >= off) v += cur[t - off];
        __syncthreads(); cur[t] = v; __syncthreads();
    }
    const int node_off = sb + cur[t] - c;
    __syncthreads();
    cur[t] = node_off;
    const int n = b * 256 + t;
    if (n < N) row_off[n] = node_off;
    if (b == gridDim.x - 1 && t == 0) row_off[N] = E;
    __syncthreads();

    for (int p = sb + t; p < se; p += 256) {
        const int v = pairs[p];
        const int pos = atomicAdd(&cur[v >> 16], 1);
        csr_src[pos] = v & 0xFFFF;
    }
}

__global__ __launch_bounds__(256) void gat_aggregate(
    const int* __restrict__ row_off, const int* __restrict__ csr_src,
    const float* __restrict__ h, const float* __restrict__ as,
    const float* __restrict__ ad, const float* __restrict__ bias,
    float* __restrict__ out, int N)
{
    const int wv = (blockIdx.x * 256 + threadIdx.x) >> 6;
    if (wv >= N) return;
    const int lane = threadIdx.x & 63;
    const int g  = lane >> 4;
    const int gl = lane & 15;
    const int d  = wv;

    const int beg = row_off[d], end = row_off[d + 1];
    const float add = ad[d];
    float  den = 0.f;
    float4 acc = {0.f, 0.f, 0.f, 0.f};
    int srcp = (beg + g < end) ? csr_src[beg + g] : 0;

    for (int e0 = beg; e0 < end; e0 += 4) {
        const bool valid = (e0 + g < end);
        const int  s     = srcp;
        const int  en    = e0 + 4 + g;
        srcp = (en < end) ? csr_src[en] : 0;
        const float  av = as[s];
        const float4 hv = *(const float4*)&h[(size_t)s * 64 + gl * 4];
        float ev = av + add;
        ev = (ev >= 0.f) ? ev : NEG_SLOPE * ev;
        const float w = valid ? __expf(ev) : 0.f;
        den += w;
        acc.x += w * hv.x; acc.y += w * hv.y;
        acc.z += w * hv.z; acc.w += w * hv.w;
    }
#pragma unroll
    for (int off = 16; off <= 32; off <<= 1) {
        acc.x += __shfl_xor(acc.x, off, 64);
        acc.y += __shfl_xor(acc.y, off, 64);
        acc.z += __shfl_xor(acc.z, off, 64);
        acc.w += __shfl_xor(acc.w, off, 64);
        den   += __shfl_xor(den,   off, 64);
    }
    if (g == 0) {
        const float4 bvv = *(const float4*)&bias[gl * 4];
        const float inv = (den > 0.f) ? (1.f / den) : 0.f;
        float4 o;
        o.x = fmaxf(acc.x * inv + bvv.x, 0.f);
        o.y = fmaxf(acc.y * inv + bvv.y, 0.f);
        o.z = fmaxf(acc.z * inv + bvv.z, 0.f);
        o.w = fmaxf(acc.w * inv + bvv.w, 0.f);
        *(float4*)&out[(size_t)d * 64 + gl * 4] = o;
    }
}

// ===========================================================================
extern "C" void kernel_launch(void* const* d_in, const int* in_sizes, int n_in,
                              void* d_out, int out_size, void* d_ws, size_t ws_size,
                              hipStream_t stream)
{
    const float* x  = (const float*)d_in[0];
    const int*   ei = (const int*)d_in[1];

    const int N = in_sizes[0] / 64;
    const int E = in_sizes[1] / 2;
    const int B = (N + 255) / 256;

    // workspace (no aliasing; pairs separate from H for the fused ordering)
    float* X       = (float*)d_ws;            // N*64
    float* H       = X + (size_t)N * 64;      // N*64
    float* AS      = H + (size_t)N * 64;      // N
    float* AD      = AS + N;                  // N
    int*   row_off = (int*)(AD + N);          // N+1
    int*   csr_src = row_off + (N + 1);       // E
    int*   bhist   = csr_src + E;             // 256
    int*   gcurs   = bhist + 256;             // 256
    int*   pairs   = gcurs + 256;             // E

    hipMemsetAsync(bhist, 0, 512 * sizeof(int), stream);

    P prm;
    prm.x = x; prm.ei = ei;
    prm.W1 = (const float*)d_in[2];  prm.as1 = (const float*)d_in[3];
    prm.ad1 = (const float*)d_in[4]; prm.b1  = (const float*)d_in[5];
    prm.W2 = (const float*)d_in[6];  prm.as2 = (const float*)d_in[7];
    prm.ad2 = (const float*)d_in[8]; prm.b2  = (const float*)d_in[9];
    prm.W3 = (const float*)d_in[10]; prm.as3 = (const float*)d_in[11];
    prm.ad3 = (const float*)d_in[12]; prm.b3 = (const float*)d_in[13];
    prm.l1W = (const float*)d_in[14]; prm.l1b = (const float*)d_in[15];
    prm.l2W = (const float*)d_in[16]; prm.l2b = (const float*)d_in[17];
    prm.out = (float*)d_out;
    prm.X = X; prm.H = H; prm.AS = AS; prm.AD = AD;
    prm.row_off = row_off; prm.csr_src = csr_src;
    prm.bhist = bhist; prm.gcurs = gcurs; prm.pairs = pairs;
    prm.N = N; prm.E = E; prm.B = B; prm.ntiles = (N + 63) / 64;

    void* kargs[] = {(void*)&prm};
    hipError_t err = hipLaunchCooperativeKernel(
        (void*)fused_all, dim3(1024), dim3(256), kargs, 0, stream);

    if (err != hipSuccess) {
        // -------- fallback: proven multi-kernel path --------
        const float* W[3]    = {prm.W1, prm.W2, prm.W3};
        const float* asrc[3] = {prm.as1, prm.as2, prm.as3};
        const float* adst[3] = {prm.ad1, prm.ad2, prm.ad3};
        const float* bia[3]  = {prm.b1, prm.b2, prm.b3};

        const int g64_grid = (N + 63) / 64;
        const int agg_grid = (N + 3) / 4;
        const int pc_grid  = (E + PC_TILE - 1) / PC_TILE;

        bucket_hist<<<256, 256, 0, stream>>>(ei, E, bhist);
        partition_coarse<<<pc_grid, 256, 0, stream>>>(ei, E, bhist, gcurs, pairs);
        fine_scatter<<<B, 256, 0, stream>>>(bhist, pairs, N, E, row_off, csr_src);

        for (int l = 0; l < 3; ++l) {
            const float* in_act = (l == 0) ? x : X;
            gemm64<false, true><<<g64_grid, 256, 0, stream>>>(
                in_act, W[l], nullptr, asrc[l], adst[l], H, AS, AD, N);
            gat_aggregate<<<agg_grid, 256, 0, stream>>>(
                row_off, csr_src, H, AS, AD, bia[l], X, N);
        }
        gemm_head<<<g64_grid, 256, 0, stream>>>(
            X, prm.l1W, prm.l1b, prm.l2W, prm.l2b, (float*)d_out, N);
    }
}

// Round 7
// 209.153 us; speedup vs baseline: 5.6550x; 5.6550x over previous
//
#include <hip/hip_runtime.h>

#define NEG_SLOPE 0.2f
#define NBUCK 256

// ===========================================================================
// Register-blocked GEMM: out[N,64] = x[N,64] @ W[64,64] (+bias) (+relu)
// 64x64 tile per block; 256 threads; 4x4 outputs/thread.
// Optionally produces alpha_s/alpha_d = (out * a).sum(-1) via 16-lane reduce.
// ===========================================================================
template <bool RELU, bool WANT_ALPHA>
__global__ __launch_bounds__(256) void gemm64(
    const float* __restrict__ x, const float* __restrict__ W,
    const float* __restrict__ bias,
    const float* __restrict__ a_src, const float* __restrict__ a_dst,
    float* __restrict__ out, float* __restrict__ alpha_s,
    float* __restrict__ alpha_d, int N)
{
    __shared__ float Xs[64][68];   // +4 pad: column reads 2-way max (free)
    __shared__ float Ws[64][64];

    const int row0 = blockIdx.x * 64;

    for (int i = threadIdx.x; i < 1024; i += 256)
        ((float4*)Ws)[i] = ((const float4*)W)[i];
    for (int i = threadIdx.x; i < 1024; i += 256) {
        int r = i >> 4, c4 = (i & 15) * 4;
        float4 v = {0.f, 0.f, 0.f, 0.f};
        if (row0 + r < N) v = *(const float4*)&x[(size_t)(row0 + r) * 64 + c4];
        *(float4*)&Xs[r][c4] = v;
    }
    __syncthreads();

    const int tx = threadIdx.x & 15;
    const int ty = threadIdx.x >> 4;

    float acc[4][4] = {{0.f,0.f,0.f,0.f},{0.f,0.f,0.f,0.f},
                       {0.f,0.f,0.f,0.f},{0.f,0.f,0.f,0.f}};

#pragma unroll 8
    for (int k = 0; k < 64; ++k) {
        const float4 wv = *(const float4*)&Ws[k][tx * 4];
        const float x0 = Xs[ty * 4 + 0][k];
        const float x1 = Xs[ty * 4 + 1][k];
        const float x2 = Xs[ty * 4 + 2][k];
        const float x3 = Xs[ty * 4 + 3][k];
        acc[0][0] += x0 * wv.x; acc[0][1] += x0 * wv.y;
        acc[0][2] += x0 * wv.z; acc[0][3] += x0 * wv.w;
        acc[1][0] += x1 * wv.x; acc[1][1] += x1 * wv.y;
        acc[1][2] += x1 * wv.z; acc[1][3] += x1 * wv.w;
        acc[2][0] += x2 * wv.x; acc[2][1] += x2 * wv.y;
        acc[2][2] += x2 * wv.z; acc[2][3] += x2 * wv.w;
        acc[3][0] += x3 * wv.x; acc[3][1] += x3 * wv.y;
        acc[3][2] += x3 * wv.z; acc[3][3] += x3 * wv.w;
    }

    float4 bv = {0.f, 0.f, 0.f, 0.f};
    if (bias) bv = *(const float4*)&bias[tx * 4];

#pragma unroll
    for (int i = 0; i < 4; ++i) {
        const int r = row0 + ty * 4 + i;
        if (r < N) {
            float4 o;
            o.x = acc[i][0] + bv.x; o.y = acc[i][1] + bv.y;
            o.z = acc[i][2] + bv.z; o.w = acc[i][3] + bv.w;
            if (RELU) {
                o.x = fmaxf(o.x, 0.f); o.y = fmaxf(o.y, 0.f);
                o.z = fmaxf(o.z, 0.f); o.w = fmaxf(o.w, 0.f);
            }
            *(float4*)&out[(size_t)r * 64 + tx * 4] = o;
        }
    }

    if (WANT_ALPHA) {
        const float4 asv = *(const float4*)&a_src[tx * 4];
        const float4 adv = *(const float4*)&a_dst[tx * 4];
#pragma unroll
        for (int i = 0; i < 4; ++i) {
            float s = acc[i][0]*asv.x + acc[i][1]*asv.y
                    + acc[i][2]*asv.z + acc[i][3]*asv.w;
            float d = acc[i][0]*adv.x + acc[i][1]*adv.y
                    + acc[i][2]*adv.z + acc[i][3]*adv.w;
#pragma unroll
            for (int off = 1; off < 16; off <<= 1) {
                s += __shfl_xor(s, off, 16);
                d += __shfl_xor(d, off, 16);
            }
            const int r = row0 + ty * 4 + i;
            if (tx == 0 && r < N) { alpha_s[r] = s; alpha_d[r] = d; }
        }
    }
}

// ===========================================================================
// Fused MLP head: out[N,32] = relu(X @ W1 + b1) @ W2 + b2
// ===========================================================================
__global__ __launch_bounds__(256) void gemm_head(
    const float* __restrict__ X, const float* __restrict__ W1,
    const float* __restrict__ b1, const float* __restrict__ W2,
    const float* __restrict__ b2, float* __restrict__ out, int N)
{
    __shared__ float Xs[64][68];
    __shared__ float W1s[64][64];
    __shared__ float W2s[64][32];

    const int row0 = blockIdx.x * 64;

    for (int i = threadIdx.x; i < 1024; i += 256)
        ((float4*)W1s)[i] = ((const float4*)W1)[i];
    for (int i = threadIdx.x; i < 512; i += 256)
        ((float4*)W2s)[i] = ((const float4*)W2)[i];
    for (int i = threadIdx.x; i < 1024; i += 256) {
        int r = i >> 4, c4 = (i & 15) * 4;
        float4 v = {0.f, 0.f, 0.f, 0.f};
        if (row0 + r < N) v = *(const float4*)&X[(size_t)(row0 + r) * 64 + c4];
        *(float4*)&Xs[r][c4] = v;
    }
    __syncthreads();

    const int tx = threadIdx.x & 15;
    const int ty = threadIdx.x >> 4;

    float acc[4][4] = {{0,0,0,0},{0,0,0,0},{0,0,0,0},{0,0,0,0}};
#pragma unroll 8
    for (int k = 0; k < 64; ++k) {
        const float4 wv = *(const float4*)&W1s[k][tx * 4];
        const float x0 = Xs[ty * 4 + 0][k];
        const float x1 = Xs[ty * 4 + 1][k];
        const float x2 = Xs[ty * 4 + 2][k];
        const float x3 = Xs[ty * 4 + 3][k];
        acc[0][0] += x0 * wv.x; acc[0][1] += x0 * wv.y;
        acc[0][2] += x0 * wv.z; acc[0][3] += x0 * wv.w;
        acc[1][0] += x1 * wv.x; acc[1][1] += x1 * wv.y;
        acc[1][2] += x1 * wv.z; acc[1][3] += x1 * wv.w;
        acc[2][0] += x2 * wv.x; acc[2][1] += x2 * wv.y;
        acc[2][2] += x2 * wv.z; acc[2][3] += x2 * wv.w;
        acc[3][0] += x3 * wv.x; acc[3][1] += x3 * wv.y;
        acc[3][2] += x3 * wv.z; acc[3][3] += x3 * wv.w;
    }

    const float4 bv = *(const float4*)&b1[tx * 4];
    __syncthreads();   // done reading Xs as X
#pragma unroll
    for (int i = 0; i < 4; ++i) {
        Xs[ty * 4 + i][tx * 4 + 0] = fmaxf(acc[i][0] + bv.x, 0.f);
        Xs[ty * 4 + i][tx * 4 + 1] = fmaxf(acc[i][1] + bv.y, 0.f);
        Xs[ty * 4 + i][tx * 4 + 2] = fmaxf(acc[i][2] + bv.z, 0.f);
        Xs[ty * 4 + i][tx * 4 + 3] = fmaxf(acc[i][3] + bv.w, 0.f);
    }
    __syncthreads();

    float a2[4][2] = {{0,0},{0,0},{0,0},{0,0}};
#pragma unroll 8
    for (int k = 0; k < 64; ++k) {
        const float2 wv = *(const float2*)&W2s[k][tx * 2];
        const float t0 = Xs[ty * 4 + 0][k];
        const float t1 = Xs[ty * 4 + 1][k];
        const float t2 = Xs[ty * 4 + 2][k];
        const float t3 = Xs[ty * 4 + 3][k];
        a2[0][0] += t0 * wv.x; a2[0][1] += t0 * wv.y;
        a2[1][0] += t1 * wv.x; a2[1][1] += t1 * wv.y;
        a2[2][0] += t2 * wv.x; a2[2][1] += t2 * wv.y;
        a2[3][0] += t3 * wv.x; a2[3][1] += t3 * wv.y;
    }
    const float2 b2v = *(const float2*)&b2[tx * 2];
#pragma unroll
    for (int i = 0; i < 4; ++i) {
        const int r = row0 + ty * 4 + i;
        if (r < N) {
            float2 o;
            o.x = a2[i][0] + b2v.x;
            o.y = a2[i][1] + b2v.y;
            *(float2*)&out[(size_t)r * 32 + tx * 2] = o;
        }
    }
}

// ===========================================================================
// CSR build: 256-bucket histogram -> coarse partition -> in-bucket scatter
// ===========================================================================
__global__ __launch_bounds__(256) void bucket_hist(
    const int* __restrict__ ei, int E, int* __restrict__ bhist)
{
    __shared__ int h[NBUCK];
    const int t = threadIdx.x;
    h[t] = 0;
    __syncthreads();
    for (int e = blockIdx.x * 256 + t; e < E; e += gridDim.x * 256)
        atomicAdd(&h[((unsigned)ei[E + e]) >> 8], 1);
    __syncthreads();
    if (h[t]) atomicAdd(&bhist[t], h[t]);
}

#define PC_EPT 8
#define PC_TILE 2048
__global__ __launch_bounds__(256) void partition_coarse(
    const int* __restrict__ ei, int E, const int* __restrict__ bhist,
    int* __restrict__ gcurs, int* __restrict__ pairs)
{
    __shared__ int sc[NBUCK];
    __shared__ int hist[NBUCK];
    __shared__ int base[NBUCK];
    const int t = threadIdx.x;

    const int bh = bhist[t];
    sc[t] = bh; __syncthreads();
    for (int off = 1; off < 256; off <<= 1) {
        int v = sc[t];
        if (t >= off) v += sc[t - off];
        __syncthreads(); sc[t] = v; __syncthreads();
    }
    const int bbase = sc[t] - bh;
    hist[t] = 0;
    __syncthreads();

    const int tile0 = blockIdx.x * PC_TILE;
    int sv[PC_EPT], dv[PC_EPT], rk[PC_EPT];
#pragma unroll
    for (int i = 0; i < PC_EPT; ++i) {
        const int e = tile0 + i * 256 + t;
        if (e < E) {
            sv[i] = ei[e];
            dv[i] = ei[E + e];
            rk[i] = atomicAdd(&hist[dv[i] >> 8], 1);
        } else dv[i] = -1;
    }
    __syncthreads();
    if (hist[t] > 0) base[t] = bbase + atomicAdd(&gcurs[t], hist[t]);
    __syncthreads();
#pragma unroll
    for (int i = 0; i < PC_EPT; ++i) {
        if (dv[i] >= 0) {
            const int b = dv[i] >> 8;
            pairs[base[b] + rk[i]] = sv[i] | ((dv[i] & 255) << 16);
        }
    }
}

__global__ __launch_bounds__(256) void fine_scatter(
    const int* __restrict__ bhist, const int* __restrict__ pairs,
    int N, int E, int* __restrict__ row_off, int* __restrict__ csr_src)
{
    __shared__ int sc[NBUCK];
    __shared__ int cnt[NBUCK];
    __shared__ int cur[NBUCK];
    const int t = threadIdx.x, b = blockIdx.x;

    const int bh = bhist[t];
    sc[t] = bh; __syncthreads();
    for (int off = 1; off < 256; off <<= 1) {
        int v = sc[t];
        if (t >= off) v += sc[t - off];
        __syncthreads(); sc[t] = v; __syncthreads();
    }
    sc[t] -= bh;
    cnt[t] = 0;
    __syncthreads();

    const int sb = sc[b];
    const int se = sb + bhist[b];

    for (int p = sb + t; p < se; p += 256)
        atomicAdd(&cnt[pairs[p] >> 16], 1);
    __syncthreads();

    const int c = cnt[t];
    cur[t] = c; __syncthreads();
    for (int off = 1; off < 256; off <<= 1) {
        int v = cur[t];
        if (t >= off) v += cur[t - off];
        __syncthreads(); cur[t] = v; __syncthreads();
    }
    const int node_off = sb + cur[t] - c;
    __syncthreads();
    cur[t] = node_off;
    const int n = b * 256 + t;
    if (n < N) row_off[n] = node_off;
    if (b == gridDim.x - 1 && t == 0) row_off[N] = E;
    __syncthreads();

    for (int p = sb + t; p < se; p += 256) {
        const int v = pairs[p];
        const int pos = atomicAdd(&cur[v >> 16], 1);
        csr_src[pos] = v & 0xFFFF;
    }
}

// ===========================================================================
// GAT aggregation v4: one wave per dst, softmax without max-shift (exact to
// fp32 rounding via shift-invariance; |e| << 88). UNROLL x2: 8 edges in
// flight per wave (two independent h-gathers per 16-lane group) to double
// the outstanding-load queue depth — the loop is gather-latency bound.
// ===========================================================================
__global__ __launch_bounds__(256) void gat_aggregate(
    const int* __restrict__ row_off, const int* __restrict__ csr_src,
    const float* __restrict__ h, const float* __restrict__ as,
    const float* __restrict__ ad, const float* __restrict__ bias,
    float* __restrict__ out, int N)
{
    const int wv = (blockIdx.x * 256 + threadIdx.x) >> 6;
    if (wv >= N) return;
    const int d    = wv;
    const int lane = threadIdx.x & 63;
    const int g    = lane >> 4;
    const int gl   = lane & 15;

    const int beg = row_off[d], end = row_off[d + 1];
    const float add = ad[d];

    float  den  = 0.f;
    float4 acc0 = {0.f, 0.f, 0.f, 0.f};
    float4 acc1 = {0.f, 0.f, 0.f, 0.f};

    // prefetch src indices one 8-edge super-chunk ahead
    int s0 = (beg     + g < end) ? csr_src[beg     + g] : 0;
    int s1 = (beg + 4 + g < end) ? csr_src[beg + 4 + g] : 0;

    for (int e0 = beg; e0 < end; e0 += 8) {
        const bool v0 = (e0     + g < end);
        const bool v1 = (e0 + 4 + g < end);
        const int  cs0 = s0, cs1 = s1;

        const int n0 = e0 +  8 + g;
        const int n1 = e0 + 12 + g;
        s0 = (n0 < end) ? csr_src[n0] : 0;
        s1 = (n1 < end) ? csr_src[n1] : 0;

        // issue both gathers + both alpha loads up front (independent)
        const float4 h0 = *(const float4*)&h[(size_t)cs0 * 64 + gl * 4];
        const float4 h1 = *(const float4*)&h[(size_t)cs1 * 64 + gl * 4];
        const float  a0 = as[cs0];
        const float  a1 = as[cs1];

        float ev0 = a0 + add;
        ev0 = (ev0 >= 0.f) ? ev0 : NEG_SLOPE * ev0;
        float ev1 = a1 + add;
        ev1 = (ev1 >= 0.f) ? ev1 : NEG_SLOPE * ev1;

        const float w0 = v0 ? __expf(ev0) : 0.f;
        const float w1 = v1 ? __expf(ev1) : 0.f;

        den += w0 + w1;
        acc0.x += w0 * h0.x; acc0.y += w0 * h0.y;
        acc0.z += w0 * h0.z; acc0.w += w0 * h0.w;
        acc1.x += w1 * h1.x; acc1.y += w1 * h1.y;
        acc1.z += w1 * h1.z; acc1.w += w1 * h1.w;
    }

    float4 acc;
    acc.x = acc0.x + acc1.x; acc.y = acc0.y + acc1.y;
    acc.z = acc0.z + acc1.z; acc.w = acc0.w + acc1.w;

    // reduce the 4 edge-groups (lanes differ in bits 4,5)
#pragma unroll
    for (int off = 16; off <= 32; off <<= 1) {
        acc.x += __shfl_xor(acc.x, off, 64);
        acc.y += __shfl_xor(acc.y, off, 64);
        acc.z += __shfl_xor(acc.z, off, 64);
        acc.w += __shfl_xor(acc.w, off, 64);
        den   += __shfl_xor(den,   off, 64);
    }

    if (g == 0) {
        const float4 bvv = *(const float4*)&bias[gl * 4];
        const float inv = (den > 0.f) ? (1.f / den) : 0.f;
        float4 o;
        o.x = fmaxf(acc.x * inv + bvv.x, 0.f);
        o.y = fmaxf(acc.y * inv + bvv.y, 0.f);
        o.z = fmaxf(acc.z * inv + bvv.z, 0.f);
        o.w = fmaxf(acc.w * inv + bvv.w, 0.f);
        *(float4*)&out[(size_t)d * 64 + gl * 4] = o;
    }
}

extern "C" void kernel_launch(void* const* d_in, const int* in_sizes, int n_in,
                              void* d_out, int out_size, void* d_ws, size_t ws_size,
                              hipStream_t stream)
{
    const float* x  = (const float*)d_in[0];
    const int*   ei = (const int*)d_in[1];
    const float* W[3]    = {(const float*)d_in[2], (const float*)d_in[6],  (const float*)d_in[10]};
    const float* asrc[3] = {(const float*)d_in[3], (const float*)d_in[7],  (const float*)d_in[11]};
    const float* adst[3] = {(const float*)d_in[4], (const float*)d_in[8],  (const float*)d_in[12]};
    const float* bia[3]  = {(const float*)d_in[5], (const float*)d_in[9],  (const float*)d_in[13]};
    const float* lin1W = (const float*)d_in[14];
    const float* lin1b = (const float*)d_in[15];
    const float* lin2W = (const float*)d_in[16];
    const float* lin2b = (const float*)d_in[17];

    const int N = in_sizes[0] / 64;
    const int E = in_sizes[1] / 2;
    const int B = (N + 255) / 256;            // coarse buckets (<=256)

    // workspace layout
    float* X       = (float*)d_ws;            // N*64
    float* H       = X + (size_t)N * 64;      // N*64 (aliased as pairs)
    float* AS      = H + (size_t)N * 64;      // N
    float* AD      = AS + N;                  // N
    int*   row_off = (int*)(AD + N);          // N+1
    int*   csr_src = row_off + (N + 1);       // E
    int*   bhist   = csr_src + E;             // 256
    int*   gcurs   = bhist + 256;             // 256
    int*   pairs   = (int*)H;                 // E ints (H dead until gemm)

    const int g64_grid = (N + 63) / 64;
    const int agg_grid = (N + 3) / 4;
    const int pc_grid  = (E + PC_TILE - 1) / PC_TILE;

    // ---- CSR build ----
    hipMemsetAsync(bhist, 0, 512 * sizeof(int), stream);
    bucket_hist<<<256, 256, 0, stream>>>(ei, E, bhist);
    partition_coarse<<<pc_grid, 256, 0, stream>>>(ei, E, bhist, gcurs, pairs);
    fine_scatter<<<B, 256, 0, stream>>>(bhist, pairs, N, E, row_off, csr_src);

    // ---- 3 GAT layers ----
    for (int l = 0; l < 3; ++l) {
        const float* in_act = (l == 0) ? x : X;
        gemm64<false, true><<<g64_grid, 256, 0, stream>>>(
            in_act, W[l], nullptr, asrc[l], adst[l], H, AS, AD, N);
        gat_aggregate<<<agg_grid, 256, 0, stream>>>(
            row_off, csr_src, H, AS, AD, bia[l], X, N);
    }

    // ---- fused MLP head ----
    gemm_head<<<g64_grid, 256, 0, stream>>>(
        X, lin1W, lin1b, lin2W, lin2b, (float*)d_out, N);
}

// Round 8
// 202.730 us; speedup vs baseline: 5.8341x; 1.0317x over previous
//
#include <hip/hip_runtime.h>

#define NEG_SLOPE 0.2f
#define NBUCK 256

// ===========================================================================
// Register-blocked GEMM: out[N,64] = x[N,64] @ W[64,64]
// 64x64 tile per block; 256 threads; 4x4 outputs/thread.
// WANT_ALPHA: also alpha_s/alpha_d = (out * a).sum(-1) via 16-lane reduce.
// DO_HIST: blocks 0..255 additionally histogram edge dst>>8 into bhist
// (fused CSR pass 0 — independent of the GEMM work).
// ===========================================================================
template <bool WANT_ALPHA, bool DO_HIST>
__global__ __launch_bounds__(256) void gemm64(
    const float* __restrict__ x, const float* __restrict__ W,
    const float* __restrict__ a_src, const float* __restrict__ a_dst,
    float* __restrict__ out, float* __restrict__ alpha_s,
    float* __restrict__ alpha_d, int N,
    const int* __restrict__ ei, int E, int* __restrict__ bhist)
{
    __shared__ float Xs[64][68];   // +4 pad: column reads 2-way max (free)
    __shared__ float Ws[64][64];
    __shared__ int   hsh[NBUCK];

    const int row0 = blockIdx.x * 64;

    for (int i = threadIdx.x; i < 1024; i += 256)
        ((float4*)Ws)[i] = ((const float4*)W)[i];
    for (int i = threadIdx.x; i < 1024; i += 256) {
        int r = i >> 4, c4 = (i & 15) * 4;
        float4 v = {0.f, 0.f, 0.f, 0.f};
        if (row0 + r < N) v = *(const float4*)&x[(size_t)(row0 + r) * 64 + c4];
        *(float4*)&Xs[r][c4] = v;
    }
    if (DO_HIST && blockIdx.x < 256) hsh[threadIdx.x] = 0;
    __syncthreads();

    const int tx = threadIdx.x & 15;
    const int ty = threadIdx.x >> 4;

    float acc[4][4] = {{0.f,0.f,0.f,0.f},{0.f,0.f,0.f,0.f},
                       {0.f,0.f,0.f,0.f},{0.f,0.f,0.f,0.f}};

#pragma unroll 8
    for (int k = 0; k < 64; ++k) {
        const float4 wv = *(const float4*)&Ws[k][tx * 4];
        const float x0 = Xs[ty * 4 + 0][k];
        const float x1 = Xs[ty * 4 + 1][k];
        const float x2 = Xs[ty * 4 + 2][k];
        const float x3 = Xs[ty * 4 + 3][k];
        acc[0][0] += x0 * wv.x; acc[0][1] += x0 * wv.y;
        acc[0][2] += x0 * wv.z; acc[0][3] += x0 * wv.w;
        acc[1][0] += x1 * wv.x; acc[1][1] += x1 * wv.y;
        acc[1][2] += x1 * wv.z; acc[1][3] += x1 * wv.w;
        acc[2][0] += x2 * wv.x; acc[2][1] += x2 * wv.y;
        acc[2][2] += x2 * wv.z; acc[2][3] += x2 * wv.w;
        acc[3][0] += x3 * wv.x; acc[3][1] += x3 * wv.y;
        acc[3][2] += x3 * wv.z; acc[3][3] += x3 * wv.w;
    }

#pragma unroll
    for (int i = 0; i < 4; ++i) {
        const int r = row0 + ty * 4 + i;
        if (r < N) {
            float4 o = {acc[i][0], acc[i][1], acc[i][2], acc[i][3]};
            *(float4*)&out[(size_t)r * 64 + tx * 4] = o;
        }
    }

    if (WANT_ALPHA) {
        const float4 asv = *(const float4*)&a_src[tx * 4];
        const float4 adv = *(const float4*)&a_dst[tx * 4];
#pragma unroll
        for (int i = 0; i < 4; ++i) {
            float s = acc[i][0]*asv.x + acc[i][1]*asv.y
                    + acc[i][2]*asv.z + acc[i][3]*asv.w;
            float d = acc[i][0]*adv.x + acc[i][1]*adv.y
                    + acc[i][2]*adv.z + acc[i][3]*adv.w;
#pragma unroll
            for (int off = 1; off < 16; off <<= 1) {
                s += __shfl_xor(s, off, 16);
                d += __shfl_xor(d, off, 16);
            }
            const int r = row0 + ty * 4 + i;
            if (tx == 0 && r < N) { alpha_s[r] = s; alpha_d[r] = d; }
        }
    }

    // fused CSR pass 0: bucket histogram (256 blocks, slice each)
    if (DO_HIST && blockIdx.x < 256) {
        __syncthreads();
        for (int e = blockIdx.x * 256 + threadIdx.x; e < E; e += 256 * 256)
            atomicAdd(&hsh[((unsigned)ei[E + e]) >> 8], 1);
        __syncthreads();
        if (hsh[threadIdx.x]) atomicAdd(&bhist[threadIdx.x], hsh[threadIdx.x]);
    }
}

// ===========================================================================
// Fused MLP head: out[N,32] = relu(X @ W1 + b1) @ W2 + b2
// ===========================================================================
__global__ __launch_bounds__(256) void gemm_head(
    const float* __restrict__ X, const float* __restrict__ W1,
    const float* __restrict__ b1, const float* __restrict__ W2,
    const float* __restrict__ b2, float* __restrict__ out, int N)
{
    __shared__ float Xs[64][68];
    __shared__ float W1s[64][64];
    __shared__ float W2s[64][32];

    const int row0 = blockIdx.x * 64;

    for (int i = threadIdx.x; i < 1024; i += 256)
        ((float4*)W1s)[i] = ((const float4*)W1)[i];
    for (int i = threadIdx.x; i < 512; i += 256)
        ((float4*)W2s)[i] = ((const float4*)W2)[i];
    for (int i = threadIdx.x; i < 1024; i += 256) {
        int r = i >> 4, c4 = (i & 15) * 4;
        float4 v = {0.f, 0.f, 0.f, 0.f};
        if (row0 + r < N) v = *(const float4*)&X[(size_t)(row0 + r) * 64 + c4];
        *(float4*)&Xs[r][c4] = v;
    }
    __syncthreads();

    const int tx = threadIdx.x & 15;
    const int ty = threadIdx.x >> 4;

    float acc[4][4] = {{0,0,0,0},{0,0,0,0},{0,0,0,0},{0,0,0,0}};
#pragma unroll 8
    for (int k = 0; k < 64; ++k) {
        const float4 wv = *(const float4*)&W1s[k][tx * 4];
        const float x0 = Xs[ty * 4 + 0][k];
        const float x1 = Xs[ty * 4 + 1][k];
        const float x2 = Xs[ty * 4 + 2][k];
        const float x3 = Xs[ty * 4 + 3][k];
        acc[0][0] += x0 * wv.x; acc[0][1] += x0 * wv.y;
        acc[0][2] += x0 * wv.z; acc[0][3] += x0 * wv.w;
        acc[1][0] += x1 * wv.x; acc[1][1] += x1 * wv.y;
        acc[1][2] += x1 * wv.z; acc[1][3] += x1 * wv.w;
        acc[2][0] += x2 * wv.x; acc[2][1] += x2 * wv.y;
        acc[2][2] += x2 * wv.z; acc[2][3] += x2 * wv.w;
        acc[3][0] += x3 * wv.x; acc[3][1] += x3 * wv.y;
        acc[3][2] += x3 * wv.z; acc[3][3] += x3 * wv.w;
    }

    const float4 bv = *(const float4*)&b1[tx * 4];
    __syncthreads();   // done reading Xs as X
#pragma unroll
    for (int i = 0; i < 4; ++i) {
        Xs[ty * 4 + i][tx * 4 + 0] = fmaxf(acc[i][0] + bv.x, 0.f);
        Xs[ty * 4 + i][tx * 4 + 1] = fmaxf(acc[i][1] + bv.y, 0.f);
        Xs[ty * 4 + i][tx * 4 + 2] = fmaxf(acc[i][2] + bv.z, 0.f);
        Xs[ty * 4 + i][tx * 4 + 3] = fmaxf(acc[i][3] + bv.w, 0.f);
    }
    __syncthreads();

    float a2[4][2] = {{0,0},{0,0},{0,0},{0,0}};
#pragma unroll 8
    for (int k = 0; k < 64; ++k) {
        const float2 wv = *(const float2*)&W2s[k][tx * 2];
        const float t0 = Xs[ty * 4 + 0][k];
        const float t1 = Xs[ty * 4 + 1][k];
        const float t2 = Xs[ty * 4 + 2][k];
        const float t3 = Xs[ty * 4 + 3][k];
        a2[0][0] += t0 * wv.x; a2[0][1] += t0 * wv.y;
        a2[1][0] += t1 * wv.x; a2[1][1] += t1 * wv.y;
        a2[2][0] += t2 * wv.x; a2[2][1] += t2 * wv.y;
        a2[3][0] += t3 * wv.x; a2[3][1] += t3 * wv.y;
    }
    const float2 b2v = *(const float2*)&b2[tx * 2];
#pragma unroll
    for (int i = 0; i < 4; ++i) {
        const int r = row0 + ty * 4 + i;
        if (r < N) {
            float2 o;
            o.x = a2[i][0] + b2v.x;
            o.y = a2[i][1] + b2v.y;
            *(float2*)&out[(size_t)r * 32 + tx * 2] = o;
        }
    }
}

// ===========================================================================
// CSR build: coarse partition -> in-bucket scatter (hist fused into gemm1)
// ===========================================================================
#define PC_EPT 8
#define PC_TILE 2048
__global__ __launch_bounds__(256) void partition_coarse(
    const int* __restrict__ ei, int E, const int* __restrict__ bhist,
    int* __restrict__ gcurs, int* __restrict__ pairs)
{
    __shared__ int sc[NBUCK];
    __shared__ int hist[NBUCK];
    __shared__ int base[NBUCK];
    const int t = threadIdx.x;

    const int bh = bhist[t];
    sc[t] = bh; __syncthreads();
    for (int off = 1; off < 256; off <<= 1) {
        int v = sc[t];
        if (t >= off) v += sc[t - off];
        __syncthreads(); sc[t] = v; __syncthreads();
    }
    const int bbase = sc[t] - bh;
    hist[t] = 0;
    __syncthreads();

    const int tile0 = blockIdx.x * PC_TILE;
    int sv[PC_EPT], dv[PC_EPT], rk[PC_EPT];
#pragma unroll
    for (int i = 0; i < PC_EPT; ++i) {
        const int e = tile0 + i * 256 + t;
        if (e < E) {
            sv[i] = ei[e];
            dv[i] = ei[E + e];
            rk[i] = atomicAdd(&hist[dv[i] >> 8], 1);
        } else dv[i] = -1;
    }
    __syncthreads();
    if (hist[t] > 0) base[t] = bbase + atomicAdd(&gcurs[t], hist[t]);
    __syncthreads();
#pragma unroll
    for (int i = 0; i < PC_EPT; ++i) {
        if (dv[i] >= 0) {
            const int b = dv[i] >> 8;
            pairs[base[b] + rk[i]] = sv[i] | ((dv[i] & 255) << 16);
        }
    }
}

__global__ __launch_bounds__(256) void fine_scatter(
    const int* __restrict__ bhist, const int* __restrict__ pairs,
    int N, int E, int* __restrict__ row_off, int* __restrict__ csr_src)
{
    __shared__ int sc[NBUCK];
    __shared__ int cnt[NBUCK];
    __shared__ int cur[NBUCK];
    const int t = threadIdx.x, b = blockIdx.x;

    const int bh = bhist[t];
    sc[t] = bh; __syncthreads();
    for (int off = 1; off < 256; off <<= 1) {
        int v = sc[t];
        if (t >= off) v += sc[t - off];
        __syncthreads(); sc[t] = v; __syncthreads();
    }
    sc[t] -= bh;
    cnt[t] = 0;
    __syncthreads();

    const int sb = sc[b];
    const int se = sb + bhist[b];

    for (int p = sb + t; p < se; p += 256)
        atomicAdd(&cnt[pairs[p] >> 16], 1);
    __syncthreads();

    const int c = cnt[t];
    cur[t] = c; __syncthreads();
    for (int off = 1; off < 256; off <<= 1) {
        int v = cur[t];
        if (t >= off) v += cur[t - off];
        __syncthreads(); cur[t] = v; __syncthreads();
    }
    const int node_off = sb + cur[t] - c;
    __syncthreads();
    cur[t] = node_off;
    const int n = b * 256 + t;
    if (n < N) row_off[n] = node_off;
    if (b == gridDim.x - 1 && t == 0) row_off[N] = E;
    __syncthreads();

    for (int p = sb + t; p < se; p += 256) {
        const int v = pairs[p];
        const int pos = atomicAdd(&cur[v >> 16], 1);
        csr_src[pos] = v & 0xFFFF;
    }
}

// ===========================================================================
// GAT aggregation v5: one wave per dst, no-max softmax (shift-invariance,
// |e| << 88). UNROLL x4: 16 edges in flight per wave — avg degree 16 means
// one iteration covers a typical node with 16 independent 256B gathers.
// ===========================================================================
__global__ __launch_bounds__(256) void gat_aggregate(
    const int* __restrict__ row_off, const int* __restrict__ csr_src,
    const float* __restrict__ h, const float* __restrict__ as,
    const float* __restrict__ ad, const float* __restrict__ bias,
    float* __restrict__ out, int N)
{
    const int wv = (blockIdx.x * 256 + threadIdx.x) >> 6;
    if (wv >= N) return;
    const int d    = wv;
    const int lane = threadIdx.x & 63;
    const int g    = lane >> 4;
    const int gl   = lane & 15;

    const int beg = row_off[d], end = row_off[d + 1];
    const float add = ad[d];

    float  den  = 0.f;
    float4 acc0 = {0.f,0.f,0.f,0.f}, acc1 = {0.f,0.f,0.f,0.f};
    float4 acc2 = {0.f,0.f,0.f,0.f}, acc3 = {0.f,0.f,0.f,0.f};

    // prefetch src indices one 16-edge super-chunk ahead
    int s0 = (beg      + g < end) ? csr_src[beg      + g] : 0;
    int s1 = (beg +  4 + g < end) ? csr_src[beg +  4 + g] : 0;
    int s2 = (beg +  8 + g < end) ? csr_src[beg +  8 + g] : 0;
    int s3 = (beg + 12 + g < end) ? csr_src[beg + 12 + g] : 0;

    for (int e0 = beg; e0 < end; e0 += 16) {
        const bool v0 = (e0      + g < end);
        const bool v1 = (e0 +  4 + g < end);
        const bool v2 = (e0 +  8 + g < end);
        const bool v3 = (e0 + 12 + g < end);
        const int cs0 = s0, cs1 = s1, cs2 = s2, cs3 = s3;

        s0 = (e0 + 16 + g < end) ? csr_src[e0 + 16 + g] : 0;
        s1 = (e0 + 20 + g < end) ? csr_src[e0 + 20 + g] : 0;
        s2 = (e0 + 24 + g < end) ? csr_src[e0 + 24 + g] : 0;
        s3 = (e0 + 28 + g < end) ? csr_src[e0 + 28 + g] : 0;

        // 4 independent gathers + 4 alpha loads issued up front
        const float4 h0 = *(const float4*)&h[(size_t)cs0 * 64 + gl * 4];
        const float4 h1 = *(const float4*)&h[(size_t)cs1 * 64 + gl * 4];
        const float4 h2 = *(const float4*)&h[(size_t)cs2 * 64 + gl * 4];
        const float4 h3 = *(const float4*)&h[(size_t)cs3 * 64 + gl * 4];
        const float  a0 = as[cs0];
        const float  a1 = as[cs1];
        const float  a2 = as[cs2];
        const float  a3 = as[cs3];

        float e0v = a0 + add; e0v = (e0v >= 0.f) ? e0v : NEG_SLOPE * e0v;
        float e1v = a1 + add; e1v = (e1v >= 0.f) ? e1v : NEG_SLOPE * e1v;
        float e2v = a2 + add; e2v = (e2v >= 0.f) ? e2v : NEG_SLOPE * e2v;
        float e3v = a3 + add; e3v = (e3v >= 0.f) ? e3v : NEG_SLOPE * e3v;

        const float w0 = v0 ? __expf(e0v) : 0.f;
        const float w1 = v1 ? __expf(e1v) : 0.f;
        const float w2 = v2 ? __expf(e2v) : 0.f;
        const float w3 = v3 ? __expf(e3v) : 0.f;

        den += (w0 + w1) + (w2 + w3);
        acc0.x += w0 * h0.x; acc0.y += w0 * h0.y;
        acc0.z += w0 * h0.z; acc0.w += w0 * h0.w;
        acc1.x += w1 * h1.x; acc1.y += w1 * h1.y;
        acc1.z += w1 * h1.z; acc1.w += w1 * h1.w;
        acc2.x += w2 * h2.x; acc2.y += w2 * h2.y;
        acc2.z += w2 * h2.z; acc2.w += w2 * h2.w;
        acc3.x += w3 * h3.x; acc3.y += w3 * h3.y;
        acc3.z += w3 * h3.z; acc3.w += w3 * h3.w;
    }

    float4 acc;
    acc.x = (acc0.x + acc1.x) + (acc2.x + acc3.x);
    acc.y = (acc0.y + acc1.y) + (acc2.y + acc3.y);
    acc.z = (acc0.z + acc1.z) + (acc2.z + acc3.z);
    acc.w = (acc0.w + acc1.w) + (acc2.w + acc3.w);

    // reduce the 4 edge-groups (lanes differ in bits 4,5)
#pragma unroll
    for (int off = 16; off <= 32; off <<= 1) {
        acc.x += __shfl_xor(acc.x, off, 64);
        acc.y += __shfl_xor(acc.y, off, 64);
        acc.z += __shfl_xor(acc.z, off, 64);
        acc.w += __shfl_xor(acc.w, off, 64);
        den   += __shfl_xor(den,   off, 64);
    }

    if (g == 0) {
        const float4 bvv = *(const float4*)&bias[gl * 4];
        const float inv = (den > 0.f) ? (1.f / den) : 0.f;
        float4 o;
        o.x = fmaxf(acc.x * inv + bvv.x, 0.f);
        o.y = fmaxf(acc.y * inv + bvv.y, 0.f);
        o.z = fmaxf(acc.z * inv + bvv.z, 0.f);
        o.w = fmaxf(acc.w * inv + bvv.w, 0.f);
        *(float4*)&out[(size_t)d * 64 + gl * 4] = o;
    }
}

extern "C" void kernel_launch(void* const* d_in, const int* in_sizes, int n_in,
                              void* d_out, int out_size, void* d_ws, size_t ws_size,
                              hipStream_t stream)
{
    const float* x  = (const float*)d_in[0];
    const int*   ei = (const int*)d_in[1];
    const float* W[3]    = {(const float*)d_in[2], (const float*)d_in[6],  (const float*)d_in[10]};
    const float* asrc[3] = {(const float*)d_in[3], (const float*)d_in[7],  (const float*)d_in[11]};
    const float* adst[3] = {(const float*)d_in[4], (const float*)d_in[8],  (const float*)d_in[12]};
    const float* bia[3]  = {(const float*)d_in[5], (const float*)d_in[9],  (const float*)d_in[13]};
    const float* lin1W = (const float*)d_in[14];
    const float* lin1b = (const float*)d_in[15];
    const float* lin2W = (const float*)d_in[16];
    const float* lin2b = (const float*)d_in[17];

    const int N = in_sizes[0] / 64;
    const int E = in_sizes[1] / 2;
    const int B = (N + 255) / 256;            // coarse buckets (<=256)

    // workspace layout
    float* X       = (float*)d_ws;            // N*64
    float* H       = X + (size_t)N * 64;      // N*64
    float* AS      = H + (size_t)N * 64;      // N
    float* AD      = AS + N;                  // N
    int*   row_off = (int*)(AD + N);          // N+1
    int*   csr_src = row_off + (N + 1);       // E
    int*   bhist   = csr_src + E;             // 256
    int*   gcurs   = bhist + 256;             // 256
    int*   pairs   = gcurs + 256;             // E (NOT aliased with H: gemm1
                                              //    runs before partition now)

    const int g64_grid = (N + 63) / 64;
    const int agg_grid = (N + 3) / 4;
    const int pc_grid  = (E + PC_TILE - 1) / PC_TILE;

    hipMemsetAsync(bhist, 0, 512 * sizeof(int), stream);

    // ---- layer 1 GEMM (+ fused bucket histogram) ----
    gemm64<true, true><<<g64_grid, 256, 0, stream>>>(
        x, W[0], asrc[0], adst[0], H, AS, AD, N, ei, E, bhist);

    // ---- CSR build ----
    partition_coarse<<<pc_grid, 256, 0, stream>>>(ei, E, bhist, gcurs, pairs);
    fine_scatter<<<B, 256, 0, stream>>>(bhist, pairs, N, E, row_off, csr_src);

    // ---- layer 1 aggregate ----
    gat_aggregate<<<agg_grid, 256, 0, stream>>>(
        row_off, csr_src, H, AS, AD, bia[0], X, N);

    // ---- layers 2,3 ----
    for (int l = 1; l < 3; ++l) {
        gemm64<true, false><<<g64_grid, 256, 0, stream>>>(
            X, W[l], asrc[l], adst[l], H, AS, AD, N, nullptr, 0, nullptr);
        gat_aggregate<<<agg_grid, 256, 0, stream>>>(
            row_off, csr_src, H, AS, AD, bia[l], X, N);
    }

    // ---- fused MLP head ----
    gemm_head<<<g64_grid, 256, 0, stream>>>(
        X, lin1W, lin1b, lin2W, lin2b, (float*)d_out, N);
}